// Round 3
// baseline (1021.283 us; speedup 1.0000x reference)
//
#include <hip/hip_runtime.h>
#include <math.h>

#define Bsz 512
#define Tsz 512
#define Fin 32
#define Hd 64

typedef float v2f __attribute__((ext_vector_type(2)));

__device__ __forceinline__ float fsig(float x){ return 1.0f/(1.0f+__expf(-x)); }
__device__ __forceinline__ float ftanh(float x){
    float ax=fabsf(x); float e=__expf(-2.0f*ax);
    float t=(1.0f-e)/(1.0f+e); return copysignf(t,x);
}

// Producer/consumer LSTM layer: 2 waves per batch row.
// wave0 (producer): pre-gates from x (no recurrence) -> 4-deep LDS ring, 2 steps ahead.
//                   x loads are wave-uniform -> scalar path, no LDS broadcast cost.
// wave1 (consumer): recurrent Whh matvec + activations + c/h; h broadcast via
//                   wave-private LDS round trip (in-order within wave, no barrier).
// One __syncthreads per step covers the ring handoff (lag-2, depth-4 => race-free).

__global__ __launch_bounds__(128, 1)
void lstm_layer0(const float* __restrict__ x,
                 const float4* __restrict__ Wih4,
                 const float4* __restrict__ Whh4,
                 const float* __restrict__ bih,
                 const float* __restrict__ bhh,
                 float* __restrict__ h1out)
{
    __shared__ float4 pring[4][Hd];
    __shared__ __align__(16) float harr[Hd];

    const int tid=threadIdx.x, lane=tid&63, wv=tid>>6, b=blockIdx.x;

    float4 wq[4][16];                      // producer uses [g][0..7], consumer [g][0..15]
    float4 bq[16];                         // producer: x quads; consumer: h broadcast quads
    float4 nx[8];                          // producer prefetch (next step's x)
    float  b4[4];
    float4 pr = {0.f,0.f,0.f,0.f};
    float  c = 0.f, hl = 0.f;

    const float4* xg = (const float4*)(x + (size_t)b*Tsz*Fin);
    float* h1row = h1out + (size_t)b*Tsz*Hd;

    if (wv==0){
        #pragma unroll
        for (int g=0; g<4; ++g){
            const int row = g*Hd + lane;
            #pragma unroll
            for (int q=0; q<8; ++q) wq[g][q] = Wih4[row*(Fin/4)+q];
            b4[g] = bih[row] + bhh[row];
        }
        #pragma unroll
        for (int q=0; q<8; ++q) bq[q] = xg[q];   // preload t=0
    } else {
        #pragma unroll
        for (int g=0; g<4; ++g){
            const int row = g*Hd + lane;
            #pragma unroll
            for (int q=0; q<16; ++q) wq[g][q] = Whh4[row*(Hd/4)+q];
        }
        #pragma unroll
        for (int q=0; q<16; ++q) bq[q] = float4{0.f,0.f,0.f,0.f};  // h(-1)=0
    }

    #pragma unroll 1
    for (int s=0; s<Tsz+2; ++s){
        if (wv==0){
            if (s < Tsz){
                if (s+1 < Tsz){
                    #pragma unroll
                    for (int q=0; q<8; ++q) nx[q] = xg[(s+1)*(Fin/4)+q];
                }
                v2f a0[4], a1[4];
                #pragma unroll
                for (int g=0; g<4; ++g){ a0[g] = v2f{b4[g], 0.f}; a1[g] = v2f{0.f,0.f}; }
                #pragma unroll
                for (int q=0; q<8; ++q){
                    v2f u = {bq[q].x, bq[q].y};
                    v2f v = {bq[q].z, bq[q].w};
                    #pragma unroll
                    for (int g=0; g<4; ++g){
                        v2f w0 = {wq[g][q].x, wq[g][q].y};
                        v2f w1 = {wq[g][q].z, wq[g][q].w};
                        a0[g] = __builtin_elementwise_fma(u, w0, a0[g]);
                        a1[g] = __builtin_elementwise_fma(v, w1, a1[g]);
                    }
                }
                float4 p;
                p.x = (a0[0].x+a0[0].y) + (a1[0].x+a1[0].y);
                p.y = (a0[1].x+a0[1].y) + (a1[1].x+a1[1].y);
                p.z = (a0[2].x+a0[2].y) + (a1[2].x+a1[2].y);
                p.w = (a0[3].x+a0[3].y) + (a1[3].x+a1[3].y);
                pring[s&3][lane] = p;
                #pragma unroll
                for (int q=0; q<8; ++q) bq[q] = nx[q];
            }
        } else {
            if (s >= 2){
                const int t = s-2;
                v2f a0[4], a1[4];
                #pragma unroll
                for (int g=0; g<4; ++g){ a0[g]=v2f{0.f,0.f}; a1[g]=v2f{0.f,0.f}; }
                #pragma unroll
                for (int q=0; q<16; ++q){
                    v2f u = {bq[q].x, bq[q].y};
                    v2f v = {bq[q].z, bq[q].w};
                    #pragma unroll
                    for (int g=0; g<4; ++g){
                        v2f w0 = {wq[g][q].x, wq[g][q].y};
                        v2f w1 = {wq[g][q].z, wq[g][q].w};
                        a0[g] = __builtin_elementwise_fma(u, w0, a0[g]);
                        a1[g] = __builtin_elementwise_fma(v, w1, a1[g]);
                    }
                }
                float gi = fsig (pr.x + (a0[0].x+a0[0].y) + (a1[0].x+a1[0].y));
                float gf = fsig (pr.y + (a0[1].x+a0[1].y) + (a1[1].x+a1[1].y));
                float gg = ftanh(pr.z + (a0[2].x+a0[2].y) + (a1[2].x+a1[2].y));
                float go = fsig (pr.w + (a0[3].x+a0[3].y) + (a1[3].x+a1[3].y));
                c  = gf*c + gi*gg;
                hl = go*ftanh(c);
                h1row[t*Hd + lane] = hl;
                harr[lane] = hl;                       // ds ops in-order within wave
                #pragma unroll
                for (int q=0; q<16; ++q) bq[q] = ((const float4*)harr)[q];
            }
            if (s>=1 && s<=Tsz) pr = pring[(s-1)&3][lane];  // prefetch next pre-gate
        }
        __syncthreads();
    }
}

__global__ __launch_bounds__(128, 1)
void lstm_layer1_fc(const float* __restrict__ h1,
                    const float4* __restrict__ Wih4,
                    const float4* __restrict__ Whh4,
                    const float* __restrict__ bih,
                    const float* __restrict__ bhh,
                    const float* __restrict__ fcW,
                    const float* __restrict__ fcb,
                    float* __restrict__ out)
{
    __shared__ float4 pring[4][Hd];
    __shared__ __align__(16) float harr[Hd];

    const int tid=threadIdx.x, lane=tid&63, wv=tid>>6, b=blockIdx.x;

    float4 wq[4][16];
    float4 bq[16];
    float4 nx[16];
    float  b4[4];
    float4 pr = {0.f,0.f,0.f,0.f};
    float  c = 0.f, hl = 0.f;

    const float4* xg = (const float4*)(h1 + (size_t)b*Tsz*Hd);

    if (wv==0){
        #pragma unroll
        for (int g=0; g<4; ++g){
            const int row = g*Hd + lane;
            #pragma unroll
            for (int q=0; q<16; ++q) wq[g][q] = Wih4[row*(Hd/4)+q];
            b4[g] = bih[row] + bhh[row];
        }
        #pragma unroll
        for (int q=0; q<16; ++q) bq[q] = xg[q];
    } else {
        #pragma unroll
        for (int g=0; g<4; ++g){
            const int row = g*Hd + lane;
            #pragma unroll
            for (int q=0; q<16; ++q) wq[g][q] = Whh4[row*(Hd/4)+q];
        }
        #pragma unroll
        for (int q=0; q<16; ++q) bq[q] = float4{0.f,0.f,0.f,0.f};
    }

    #pragma unroll 1
    for (int s=0; s<Tsz+2; ++s){
        if (wv==0){
            if (s < Tsz){
                if (s+1 < Tsz){
                    #pragma unroll
                    for (int q=0; q<16; ++q) nx[q] = xg[(s+1)*(Hd/4)+q];
                }
                v2f a0[4], a1[4];
                #pragma unroll
                for (int g=0; g<4; ++g){ a0[g] = v2f{b4[g], 0.f}; a1[g] = v2f{0.f,0.f}; }
                #pragma unroll
                for (int q=0; q<16; ++q){
                    v2f u = {bq[q].x, bq[q].y};
                    v2f v = {bq[q].z, bq[q].w};
                    #pragma unroll
                    for (int g=0; g<4; ++g){
                        v2f w0 = {wq[g][q].x, wq[g][q].y};
                        v2f w1 = {wq[g][q].z, wq[g][q].w};
                        a0[g] = __builtin_elementwise_fma(u, w0, a0[g]);
                        a1[g] = __builtin_elementwise_fma(v, w1, a1[g]);
                    }
                }
                float4 p;
                p.x = (a0[0].x+a0[0].y) + (a1[0].x+a1[0].y);
                p.y = (a0[1].x+a0[1].y) + (a1[1].x+a1[1].y);
                p.z = (a0[2].x+a0[2].y) + (a1[2].x+a1[2].y);
                p.w = (a0[3].x+a0[3].y) + (a1[3].x+a1[3].y);
                pring[s&3][lane] = p;
                #pragma unroll
                for (int q=0; q<16; ++q) bq[q] = nx[q];
            }
        } else {
            if (s >= 2){
                v2f a0[4], a1[4];
                #pragma unroll
                for (int g=0; g<4; ++g){ a0[g]=v2f{0.f,0.f}; a1[g]=v2f{0.f,0.f}; }
                #pragma unroll
                for (int q=0; q<16; ++q){
                    v2f u = {bq[q].x, bq[q].y};
                    v2f v = {bq[q].z, bq[q].w};
                    #pragma unroll
                    for (int g=0; g<4; ++g){
                        v2f w0 = {wq[g][q].x, wq[g][q].y};
                        v2f w1 = {wq[g][q].z, wq[g][q].w};
                        a0[g] = __builtin_elementwise_fma(u, w0, a0[g]);
                        a1[g] = __builtin_elementwise_fma(v, w1, a1[g]);
                    }
                }
                float gi = fsig (pr.x + (a0[0].x+a0[0].y) + (a1[0].x+a1[0].y));
                float gf = fsig (pr.y + (a0[1].x+a0[1].y) + (a1[1].x+a1[1].y));
                float gg = ftanh(pr.z + (a0[2].x+a0[2].y) + (a1[2].x+a1[2].y));
                float go = fsig (pr.w + (a0[3].x+a0[3].y) + (a1[3].x+a1[3].y));
                c  = gf*c + gi*gg;
                hl = go*ftanh(c);
                harr[lane] = hl;
                #pragma unroll
                for (int q=0; q<16; ++q) bq[q] = ((const float4*)harr)[q];
            }
            if (s>=1 && s<=Tsz) pr = pring[(s-1)&3][lane];
        }
        __syncthreads();
    }

    if (wv==1){
        float p = hl * fcW[lane];
        #pragma unroll
        for (int off=32; off>0; off>>=1) p += __shfl_down(p, off);
        if (lane==0) out[b] = p + fcb[0];
    }
}

extern "C" void kernel_launch(void* const* d_in, const int* in_sizes, int n_in,
                              void* d_out, int out_size, void* d_ws, size_t ws_size,
                              hipStream_t stream)
{
    const float* x    = (const float*)d_in[0];
    const float* Wih0 = (const float*)d_in[1];
    const float* Whh0 = (const float*)d_in[2];
    const float* bih0 = (const float*)d_in[3];
    const float* bhh0 = (const float*)d_in[4];
    const float* Wih1 = (const float*)d_in[5];
    const float* Whh1 = (const float*)d_in[6];
    const float* bih1 = (const float*)d_in[7];
    const float* bhh1 = (const float*)d_in[8];
    const float* fcW  = (const float*)d_in[9];
    const float* fcb  = (const float*)d_in[10];
    float* out = (float*)d_out;
    float* h1  = (float*)d_ws; // B*T*H fp32 = 64 MB scratch

    lstm_layer0<<<dim3(Bsz), dim3(128), 0, stream>>>(
        x, (const float4*)Wih0, (const float4*)Whh0, bih0, bhh0, h1);
    lstm_layer1_fc<<<dim3(Bsz), dim3(128), 0, stream>>>(
        h1, (const float4*)Wih1, (const float4*)Whh1, bih1, bhh1, fcW, fcb, out);
}